// Round 2
// baseline (41886.078 us; speedup 1.0000x reference)
//
#include <hip/hip_runtime.h>

typedef __bf16 bf16x8 __attribute__((ext_vector_type(8)));
typedef float f32x4 __attribute__((ext_vector_type(4)));
typedef unsigned short u16;
typedef unsigned int u32;

#define MFMA16(a, b, c) __builtin_amdgcn_mfma_f32_16x16x32_bf16((a), (b), (c), 0, 0, 0)

// ---------------------------------------------------------------------------
// Shapes: x(256,128,512) h0(1,128,512) W0(1024,1024) Ws(8,512,1024), all f32.
// out: hiddens(256,128,512) ++ h_last(1,128,512) = 16842752 f32.
//
// ws layout:
//   bytes [0,4096)    : barrier counters (u32): sub[c] at u32 index 64*c (c<8), top at 512
//   u16   Wh[5242880] : weight hi fragments (B-fragment-major, (c,h)-interleaved cols)
//   u16   Wl[5242880] : weight lo fragments
//   u16   S[9][131072]: state slots, A-fragment-major, per-lane interleave [8 hi | 8 lo]
// slots: 0=h, 1=s0, 2=s1, 3=s2, 4=s3, 5=s4, 6=s5, 7=s7, 8=x_t
// total = 4096 + 4*5242880 + 2*1179648 = 23,334,912 bytes
//
// All cross-workgroup traffic (weights, states) uses sc0 sc1 loads/stores
// (device-scope, via LLC) -> no cache-maintenance fences needed; barriers can
// be fully relaxed atomics (ordering comes from the pre-s_barrier vmcnt drain).
// Grid: 256 blocks x 256 threads = 1 block/CU (co-residency guaranteed).
// ---------------------------------------------------------------------------

__device__ __forceinline__ u16 f2bf(float f) {
  u32 u = __float_as_uint(f);
  u += 0x7FFFu + ((u >> 16) & 1u);
  return (u16)(u >> 16);
}
__device__ __forceinline__ float bf2f(u32 h) { return __uint_as_float(h << 16); }
__device__ __forceinline__ void splitbf(float f, u16 &hi, u16 &lo) {
  hi = f2bf(f);
  lo = f2bf(f - bf2f((u32)hi));
}

// device-scope (cross-XCD coherent via LLC) memory ops
__device__ __forceinline__ void issue_ld128_sc(bf16x8 &dst, const u16 *p) {
  asm volatile("global_load_dwordx4 %0, %1, off sc0 sc1" : "=v"(dst) : "v"(p));
}
__device__ __forceinline__ void issue_ldu16_sc(u32 &dst, const u16 *p) {
  asm volatile("global_load_ushort %0, %1, off sc0 sc1" : "=v"(dst) : "v"(p));
}
__device__ __forceinline__ void wait_vm() {
  asm volatile("s_waitcnt vmcnt(0)" ::: "memory");
  __builtin_amdgcn_sched_barrier(0);
}
__device__ __forceinline__ void st16_sc(u16 *p, u16 v) {
  u32 q = v;
  asm volatile("global_store_short %0, %1, off sc0 sc1" :: "v"(p), "v"(q) : "memory");
}

__device__ __forceinline__ int mbase(int m) {          // fragment base (u16 elems)
  return m == 0 ? 0 : 1048576 + (m - 1) * 524288;      // W0 has K=1024, Ws K=512
}
// element (row, col j) -> u16 offset of hi within S (lo at +8)
__device__ __forceinline__ int eltoff(int slot, int row, int j) {
  return slot * 131072 +
         (((row >> 4) * 16 + (j >> 5)) * 64 + (row & 15) + ((j >> 3) & 3) * 16) * 16 + (j & 7);
}

template <int A> __device__ __forceinline__ float actf(float x) {
  if (A == 0) { float e = __expf(2.f * x); return 1.f - 2.f / (e + 1.f); } // tanh
  if (A == 1) return 1.f / (1.f + __expf(-x));                            // sigmoid
  if (A == 2) return fmaxf(x, 0.f);                                       // relu
  return x;                                                               // identity
}

__device__ __forceinline__ void issue_sp(const u16 *S, int slot, int rt, int cb,
                                         int l4, int l15, u32 *sph, u32 *spl) {
#pragma unroll
  for (int j = 0; j < 4; ++j) {
    int row = rt * 16 + l4 * 4 + j;
    int scol = cb * 8 + (l15 >> 1);
    const u16 *p = S + eltoff(slot, row, scol);
    issue_ldu16_sc(sph[j], p);
    issue_ldu16_sc(spl[j], p + 8);
  }
}

// D layout: col = lane&15 (even=c, odd=h via interleaved W cols), row = (lane>>4)*4 + j
template <int ACT>
__device__ __forceinline__ void act_phase(f32x4 acc, const u32 *sph, const u32 *spl,
                                          u16 *S, int dslot, int rt, int cb, int l4, int l15,
                                          float *sv, bool store) {
#pragma unroll
  for (int j = 0; j < 4; ++j) {
    float cp = acc[j];
    float hp = __shfl_xor(cp, 1);
    float spv = bf2f(sph[j]) + bf2f(spl[j]);
    float sig = 1.f / (1.f + __expf(-cp));
    float sval = spv + sig * (actf<ACT>(hp) - spv);
    sv[j] = sval;
    if (store && ((l15 & 1) == 0)) {
      int row = rt * 16 + l4 * 4 + j;
      int scol = cb * 8 + (l15 >> 1);
      u16 hi, lo; splitbf(sval, hi, lo);
      u16 *p = S + eltoff(dslot, row, scol);
      st16_sc(p, hi);
      st16_sc(p + 8, lo);
    }
  }
}

// one K=512 GEMM round tile-pair: acc += Ah*Wh + Ah*Wl + Al*Wh, fused activation
template <int ACT0, int ACT1, bool TWO>
__device__ __forceinline__ void round_k512(const u16 *Wh, const u16 *Wl, u16 *S,
                                           int aslot, int spslot, int m0, int m1, int d0, int d1,
                                           int rt, int cb, int ln, int l4, int l15,
                                           float *sv0, float *sv1, bool store) {
  u32 sph[4], spl[4];
  issue_sp(S, spslot, rt, cb, l4, l15, sph, spl);
  bf16x8 Ah[16], Al[16];
#pragma unroll
  for (int kc = 0; kc < 16; ++kc) {
    const u16 *ap = S + aslot * 131072 + ((rt * 16 + kc) * 64 + ln) * 16;
    issue_ld128_sc(Ah[kc], ap);
    issue_ld128_sc(Al[kc], ap + 8);
  }
  wait_vm();
  f32x4 acc0 = {0.f, 0.f, 0.f, 0.f}, acc1 = {0.f, 0.f, 0.f, 0.f};
  const int mb0 = mbase(m0), mb1 = mbase(m1);
#pragma unroll
  for (int kc = 0; kc < 16; ++kc) {
    int bo0 = mb0 + ((cb * 16 + kc) * 64 + ln) * 8;
    bf16x8 b0h, b0l;
    issue_ld128_sc(b0h, Wh + bo0);
    issue_ld128_sc(b0l, Wl + bo0);
    bf16x8 b1h, b1l;
    if (TWO) {
      int bo1 = mb1 + ((cb * 16 + kc) * 64 + ln) * 8;
      issue_ld128_sc(b1h, Wh + bo1);
      issue_ld128_sc(b1l, Wl + bo1);
    }
    wait_vm();
    acc0 = MFMA16(Ah[kc], b0h, acc0);
    acc0 = MFMA16(Ah[kc], b0l, acc0);
    acc0 = MFMA16(Al[kc], b0h, acc0);
    if (TWO) {
      acc1 = MFMA16(Ah[kc], b1h, acc1);
      acc1 = MFMA16(Ah[kc], b1l, acc1);
      acc1 = MFMA16(Al[kc], b1h, acc1);
    }
  }
  act_phase<ACT0>(acc0, sph, spl, S, d0, rt, cb, l4, l15, sv0, store);
  if (TWO) act_phase<ACT1>(acc1, sph, spl, S, d1, rt, cb, l4, l15, sv1, store);
}

// round A: s0 = h + sigmoid(c)*(tanh(h0) - h), A = [x | h], K=1024, W0
__device__ __forceinline__ void round_A(const u16 *Wh, const u16 *Wl, u16 *S,
                                        int rt, int cb, int ln, int l4, int l15) {
  u32 sph[4], spl[4];
  issue_sp(S, 0, rt, cb, l4, l15, sph, spl);
  f32x4 acc = {0.f, 0.f, 0.f, 0.f};
#pragma unroll
  for (int half = 0; half < 2; ++half) {
    const int aslot = half ? 0 : 8;  // k<512: x frags, k>=512: h frags
    bf16x8 Ah[16], Al[16];
#pragma unroll
    for (int kc = 0; kc < 16; ++kc) {
      const u16 *ap = S + aslot * 131072 + ((rt * 16 + kc) * 64 + ln) * 16;
      issue_ld128_sc(Ah[kc], ap);
      issue_ld128_sc(Al[kc], ap + 8);
    }
    wait_vm();
#pragma unroll
    for (int kc = 0; kc < 16; ++kc) {
      int bo = ((cb * 32 + (half * 16 + kc)) * 64 + ln) * 8;  // W0 base = 0, K=1024
      bf16x8 bh, bl;
      issue_ld128_sc(bh, Wh + bo);
      issue_ld128_sc(bl, Wl + bo);
      wait_vm();
      acc = MFMA16(Ah[kc], bh, acc);
      acc = MFMA16(Ah[kc], bl, acc);
      acc = MFMA16(Al[kc], bh, acc);
    }
  }
  float sv[4];
  act_phase<0>(acc, sph, spl, S, 1, rt, cb, l4, l15, sv, true);
}

__device__ __forceinline__ void xconv_elem(int g, int tt, const float *xin, u16 *S) {
  int rt = g >> 13, kc = (g >> 9) & 15, lnn = (g >> 3) & 63, el = g & 7;
  int row = rt * 16 + (lnn & 15);
  int k = kc * 32 + (lnn >> 4) * 8 + el;
  float v = xin[(tt * 128 + row) * 512 + k];
  u16 hi, lo; splitbf(v, hi, lo);
  int off = 8 * 131072 + ((rt * 16 + kc) * 64 + lnn) * 16 + el;
  st16_sc(S + off, hi);
  st16_sc(S + off + 8, lo);
}

// hierarchical epoch barrier over 256 WGs (8 clusters x 32). All data traffic
// is sc0/sc1 (LLC-coherent) and drained by the pre-s_barrier vmcnt(0), so the
// counter atomics can be fully relaxed.
__device__ __forceinline__ void gbar(u32 *cnt, u32 &ep) {
  __syncthreads();  // drains vmcnt for all waves -> sc-stores are at LLC
  ep += 256u;
  if (threadIdx.x == 0) {
    const int c = blockIdx.x & 7;
    u32 old = __hip_atomic_fetch_add(&cnt[c * 64], 1u, __ATOMIC_RELAXED, __HIP_MEMORY_SCOPE_AGENT);
    if (((old + 1u) & 31u) == 0u)
      __hip_atomic_fetch_add(&cnt[512], 32u, __ATOMIC_RELAXED, __HIP_MEMORY_SCOPE_AGENT);
    while (__hip_atomic_load(&cnt[512], __ATOMIC_RELAXED, __HIP_MEMORY_SCOPE_AGENT) < ep)
      __builtin_amdgcn_s_sleep(2);
  }
  __syncthreads();
}

__global__ __launch_bounds__(256, 1) void darts_rnn(
    const float *__restrict__ xin, const float *__restrict__ h0in,
    const float *__restrict__ W0, const float *__restrict__ Wsi,
    float *__restrict__ out, u16 *__restrict__ wsu) {
  u32 *cnt = (u32 *)wsu;
  u16 *Wh = wsu + 2048;          // byte 4096
  u16 *Wl = Wh + 5242880;
  u16 *S = Wl + 5242880;

  const int tid = threadIdx.x;
  const int gid = blockIdx.x * 256 + tid;      // 0..65535
  const int ln = tid & 63;
  const int w = blockIdx.x * 4 + (tid >> 6);   // global wave id, 0..1023
  const int l15 = ln & 15, l4 = ln >> 4;

  // ---- P0: weight hi/lo split into fragment layout (runs every launch) ----
  for (int e = gid; e < 5242880; e += 65536) {
    int m, r2, cb;
    if (e < 1048576) { m = 0; cb = e >> 14; r2 = e & 16383; }
    else { int r0 = e - 1048576; m = 1 + (r0 >> 19); int r = r0 & 524287; cb = r >> 13; r2 = r & 8191; }
    int kc = r2 >> 9, lnn = (r2 >> 3) & 63, el = r2 & 7;
    int colp = cb * 16 + (lnn & 15);          // interleaved: even=c-col, odd=h-col
    int k = kc * 32 + (lnn >> 4) * 8 + el;
    int oc = (colp & 1) * 512 + (colp >> 1);
    float v = (m == 0) ? W0[k * 1024 + oc] : Wsi[((m - 1) * 512 + k) * 1024 + oc];
    u16 hi, lo; splitbf(v, hi, lo);
    st16_sc(Wh + e, hi);       // sc stores: land in LLC, visible to all XCDs
    st16_sc(Wl + e, lo);
  }
  {  // h0 -> slot 0
    int g = gid;
    int rt = g >> 13, kc = (g >> 9) & 15, lnn = (g >> 3) & 63, el = g & 7;
    int row = rt * 16 + (lnn & 15), k = kc * 32 + (lnn >> 4) * 8 + el;
    float v = h0in[row * 512 + k];
    u16 hi, lo; splitbf(v, hi, lo);
    int off = ((rt * 16 + kc) * 64 + lnn) * 16 + el;
    st16_sc(S + off, hi);
    st16_sc(S + off + 8, lo);
  }
  xconv_elem(gid, 0, xin, S);  // x[0] -> slot 8

  u32 ep = 0;
  gbar(cnt, ep);               // init barrier (counters zeroed by hipMemsetAsync)

  for (int t = 0; t < 256; ++t) {
    float dum0[4], dum1[4];
    // ---- round A: s0 (slot1) ----
    if (w < 512) { int rt = w >> 6, cb = w & 63; round_A(Wh, Wl, S, rt, cb, ln, l4, l15); }
    gbar(cnt, ep);
    // ---- round B: s1 = s0 + sig*(sigmoid - s0)  [Ws0] ----
    if (w < 512) {
      int rt = w >> 6, cb = w & 63;
      round_k512<1, 1, false>(Wh, Wl, S, 1, 1, 1, 1, 2, 2, rt, cb, ln, l4, l15, dum0, dum1, true);
    }
    gbar(cnt, ep);
    // ---- round C: s2(relu,Ws1), s3(relu,Ws2), s4(ident,Ws3); A = s1 ----
    if (w < 512) {
      int rt = w >> 6, cb = w & 63;
      round_k512<2, 3, true>(Wh, Wl, S, 2, 2, 2, 4, 3, 5, rt, cb, ln, l4, l15, dum0, dum1, true);
    } else {
      int w2 = w - 512, rt = w2 >> 6, cb = w2 & 63;
      round_k512<2, 2, false>(Wh, Wl, S, 2, 2, 3, 3, 4, 4, rt, cb, ln, l4, l15, dum0, dum1, true);
    }
    gbar(cnt, ep);
    // ---- round D: s5 = f(s2; Ws4, tanh), s7 = f(s3; Ws6, tanh) ----
    if (w < 512) {
      int rt = w >> 6, cb = w & 63;
      round_k512<0, 0, false>(Wh, Wl, S, 3, 3, 5, 5, 6, 6, rt, cb, ln, l4, l15, dum0, dum1, true);
    } else {
      int w2 = w - 512, rt = w2 >> 6, cb = w2 & 63;
      round_k512<0, 0, false>(Wh, Wl, S, 4, 4, 7, 7, 7, 7, rt, cb, ln, l4, l15, dum0, dum1, true);
    }
    gbar(cnt, ep);
    // ---- round E: s6 (sig, Ws5), s8 (relu, Ws7) from s5; fused mean -> out[t], h ----
    if (w < 512) {
      int rt = w >> 6, cb = w & 63;
      float sv6[4], sv8[4];
      round_k512<1, 2, true>(Wh, Wl, S, 6, 6, 6, 8, 0, 0, rt, cb, ln, l4, l15, sv6, sv8, false);
      u32 mh[6][4], ml[6][4];
#pragma unroll
      for (int s = 0; s < 6; ++s) {
#pragma unroll
        for (int j = 0; j < 4; ++j) {
          int row = rt * 16 + l4 * 4 + j;
          int scol = cb * 8 + (l15 >> 1);
          const u16 *p = S + eltoff(s + 2, row, scol);  // slots 2..7 = s1..s5,s7
          issue_ldu16_sc(mh[s][j], p);
          issue_ldu16_sc(ml[s][j], p + 8);
        }
      }
      wait_vm();
      if ((l15 & 1) == 0) {
#pragma unroll
        for (int j = 0; j < 4; ++j) {
          float sum = sv6[j] + sv8[j];
#pragma unroll
          for (int s = 0; s < 6; ++s) sum += bf2f(mh[s][j]) + bf2f(ml[s][j]);
          float hnew = sum * 0.125f;
          int row = rt * 16 + l4 * 4 + j;
          int scol = cb * 8 + (l15 >> 1);
          out[t * 65536 + row * 512 + scol] = hnew;
          if (t == 255) out[16777216 + row * 512 + scol] = hnew;
          u16 hi, lo; splitbf(hnew, hi, lo);
          u16 *p = S + eltoff(0, row, scol);
          st16_sc(p, hi);
          st16_sc(p + 8, lo);
        }
      }
    } else if (t < 255) {  // idle waves pre-convert x[t+1] into slot 8
      int base = (w - 512) * 128 + ln * 2;
      xconv_elem(base, t + 1, xin, S);
      xconv_elem(base + 1, t + 1, xin, S);
    }
    gbar(cnt, ep);
  }
}

extern "C" void kernel_launch(void *const *d_in, const int *in_sizes, int n_in,
                              void *d_out, int out_size, void *d_ws, size_t ws_size,
                              hipStream_t stream) {
  const float *x = (const float *)d_in[0];
  const float *h0 = (const float *)d_in[1];
  const float *W0 = (const float *)d_in[2];
  const float *Ws = (const float *)d_in[3];
  float *out = (float *)d_out;
  u16 *ws = (u16 *)d_ws;

  hipMemsetAsync(d_ws, 0, 4096, stream);  // zero barrier counters (captured OK)

  void *args[] = {(void *)&x, (void *)&h0, (void *)&W0, (void *)&Ws, (void *)&out, (void *)&ws};
  hipError_t err = hipLaunchCooperativeKernel((void *)darts_rnn, dim3(256), dim3(256),
                                              args, 0, stream);
  if (err != hipSuccess) {
    (void)hipGetLastError();  // clear error state
    // Fallback: plain launch. 256 blocks x 256 thr = 1 block/CU -> co-resident
    // by construction (4 waves, 0 LDS always fit one CU), so the in-kernel
    // barrier remains safe.
    darts_rnn<<<dim3(256), dim3(256), 0, stream>>>(x, h0, W0, Ws, out, ws);
  }
}

// Round 4
// 24653.889 us; speedup vs baseline: 1.6990x; 1.6990x over previous
//
#include <hip/hip_runtime.h>

typedef __bf16 bf16x8 __attribute__((ext_vector_type(8)));
typedef float f32x4 __attribute__((ext_vector_type(4)));
typedef unsigned short u16;
typedef unsigned int u32;

#define MFMA16(a, b, c) __builtin_amdgcn_mfma_f32_16x16x32_bf16((a), (b), (c), 0, 0, 0)

// ---------------------------------------------------------------------------
// ws layout (u16 units unless noted):
//   bytes [0,4096)   : barrier counters (u32): sub[c] at u32 idx 64*c (c<8), top at 512
//   Wh[5242880]      : weight hi fragments (B-frag-major, (c,h)-interleaved cols)
//   Wl[5242880]      : weight lo fragments
//   S[8][131072]     : state slots; per (slot,rt): 16384 u16 = hi-plane[8192] ++ lo-plane[8192]
//                      line L (=kc*64+ln) at L*8..L*8+8 (hi), +8192 (lo)
// slots: 0=h, 1=s0, 2=s1, 3=s2, 4=s3, 5=s4, 6=s5, 7=s7
//
// Coherence plan: weights+states WRITTEN with sc0sc1 (to LLC). States READ with
// sc0sc1 (always fresh). Weights READ with plain cached loads (L2-resident).
// Poison / stale-L2 hazard killed once per launch: buffer_wbl2 -> gbar -> buffer_inv.
// Grid: 256 blocks x 256 threads = 1 block/CU (co-residency by construction).
// ---------------------------------------------------------------------------

__device__ __forceinline__ u16 f2bf(float f) {
  u32 u = __float_as_uint(f);
  u += 0x7FFFu + ((u >> 16) & 1u);
  return (u16)(u >> 16);
}
__device__ __forceinline__ float bf2f(u32 h) { return __uint_as_float(h << 16); }
__device__ __forceinline__ void splitbf(float f, u16 &hi, u16 &lo) {
  hi = f2bf(f);
  lo = f2bf(f - bf2f((u32)hi));
}

__device__ __forceinline__ void issue_ld128_sc(bf16x8 &d, const u16 *p) {
  asm volatile("global_load_dwordx4 %0, %1, off sc0 sc1" : "=v"(d) : "v"(p));
}
__device__ __forceinline__ void issue_ldu16_sc(u32 &d, const u16 *p) {
  asm volatile("global_load_ushort %0, %1, off sc0 sc1" : "=v"(d) : "v"(p));
}
__device__ __forceinline__ void wait_vm() {
  asm volatile("s_waitcnt vmcnt(0)" ::: "memory");
  __builtin_amdgcn_sched_barrier(0);
}
__device__ __forceinline__ void st16_sc(u16 *p, u16 v) {
  u32 q = v;
  asm volatile("global_store_short %0, %1, off sc0 sc1" :: "v"(p), "v"(q) : "memory");
}

__device__ __forceinline__ int mbase(int m) {          // u16 elems; m=0 -> W0 (K=1024)
  return m == 0 ? 0 : 1048576 + (m - 1) * 524288;
}
__device__ __forceinline__ int lineOf(int row15, int scol) {
  return (scol >> 5) * 64 + row15 + ((scol >> 3) & 3) * 16;
}
__device__ __forceinline__ int goff(int slot, int row, int scol) {  // hi elem; lo at +8192
  return slot * 131072 + (row >> 4) * 16384 + lineOf(row & 15, scol) * 8 + (scol & 7);
}

template <int A> __device__ __forceinline__ float actf(float x) {
  if (A == 0) { float e = __expf(2.f * x); return 1.f - 2.f / (e + 1.f); } // tanh
  if (A == 1) return 1.f / (1.f + __expf(-x));                            // sigmoid
  if (A == 2) return fmaxf(x, 0.f);                                       // relu
  return x;                                                               // identity
}

__device__ __forceinline__ float lds_elem(const u16 *lds, int row15, int scol) {
  int o = lineOf(row15, scol) * 8 + (scol & 7);
  return bf2f(lds[o]) + bf2f(lds[o + 8192]);
}

// copy one (slot,rt) 32KB panel global->LDS (layouts identical)
__device__ __forceinline__ void stage_panel(const u16 *S, int slot, int rt, u16 *lds, int tid) {
  const u16 *src = S + slot * 131072 + rt * 16384 + tid * 8;
  bf16x8 r[8];
#pragma unroll
  for (int i = 0; i < 8; ++i) issue_ld128_sc(r[i], src + i * 2048);
  wait_vm();
#pragma unroll
  for (int i = 0; i < 8; ++i) *(bf16x8 *)(lds + tid * 8 + i * 2048) = r[i];
}

template <int ACT, bool STORE>
__device__ __forceinline__ void act2(f32x4 acc, const float *spv, u16 *S, int dslot,
                                     int rt, int cb, int l4, int l15, float *sv) {
#pragma unroll
  for (int j = 0; j < 4; ++j) {
    float cp = acc[j];
    float hp = __shfl_xor(cp, 1);
    float sig = 1.f / (1.f + __expf(-cp));
    float sval = spv[j] + sig * (actf<ACT>(hp) - spv[j]);
    sv[j] = sval;
    if (STORE && ((l15 & 1) == 0)) {
      int row = rt * 16 + l4 * 4 + j, scol = cb * 8 + (l15 >> 1);
      u16 hi, lo; splitbf(sval, hi, lo);
      int o = goff(dslot, row, scol);
      st16_sc(S + o, hi);
      st16_sc(S + o + 8192, lo);
    }
  }
}

// K=512 GEMM round; A-panel (and s_prev) from LDS; weights plain cached loads
template <int ACT0, int ACT1, bool TWO, bool ST>
__device__ __forceinline__ void gemm512(const u16 *Wh, const u16 *Wl, u16 *S, const u16 *lds,
                                        int m0, int m1, int d0, int d1,
                                        int rt, int cb, int ln, int l4, int l15,
                                        float *sv0, float *sv1) {
  float spv[4];
#pragma unroll
  for (int j = 0; j < 4; ++j) spv[j] = lds_elem(lds, l4 * 4 + j, cb * 8 + (l15 >> 1));
  f32x4 acc0 = {0.f, 0.f, 0.f, 0.f}, acc1 = {0.f, 0.f, 0.f, 0.f};
  const u16 *w0h = Wh + mbase(m0) + (cb * 16 * 64 + ln) * 8;
  const u16 *w0l = Wl + mbase(m0) + (cb * 16 * 64 + ln) * 8;
  const u16 *w1h = Wh + mbase(m1) + (cb * 16 * 64 + ln) * 8;
  const u16 *w1l = Wl + mbase(m1) + (cb * 16 * 64 + ln) * 8;
#pragma unroll
  for (int kc = 0; kc < 16; ++kc) {
    bf16x8 Ah = *(const bf16x8 *)(lds + (kc * 64 + ln) * 8);
    bf16x8 Al = *(const bf16x8 *)(lds + 8192 + (kc * 64 + ln) * 8);
    bf16x8 b0h = *(const bf16x8 *)(w0h + kc * 512);
    bf16x8 b0l = *(const bf16x8 *)(w0l + kc * 512);
    acc0 = MFMA16(Ah, b0h, acc0);
    acc0 = MFMA16(Ah, b0l, acc0);
    acc0 = MFMA16(Al, b0h, acc0);
    if (TWO) {
      bf16x8 b1h = *(const bf16x8 *)(w1h + kc * 512);
      bf16x8 b1l = *(const bf16x8 *)(w1l + kc * 512);
      acc1 = MFMA16(Ah, b1h, acc1);
      acc1 = MFMA16(Ah, b1l, acc1);
      acc1 = MFMA16(Al, b1h, acc1);
    }
  }
  act2<ACT0, ST>(acc0, spv, S, d0, rt, cb, l4, l15, sv0);
  if (TWO) act2<ACT1, ST>(acc1, spv, S, d1, rt, cb, l4, l15, sv1);
}

// round A: s0 = h + sigmoid(c)*(tanh(h0) - h); A = [x_t | h], K=1024, W0
__device__ __forceinline__ void roundA(const float *xin, int t, const u16 *Wh, const u16 *Wl,
                                       u16 *S, const u16 *lds,
                                       int rt, int cb, int ln, int l4, int l15) {
  float spv[4];
#pragma unroll
  for (int j = 0; j < 4; ++j) spv[j] = lds_elem(lds, l4 * 4 + j, cb * 8 + (l15 >> 1));
  f32x4 acc = {0.f, 0.f, 0.f, 0.f};
  const u16 *wh = Wh + (cb * 32 * 64 + ln) * 8;
  const u16 *wl = Wl + (cb * 32 * 64 + ln) * 8;
  const float *xp = xin + (t * 128 + rt * 16 + l15) * 512 + l4 * 8;
  // k < 512: x half, fragments converted on the fly from global (plain cached)
#pragma unroll
  for (int kc = 0; kc < 16; ++kc) {
    f32x4 xa = *(const f32x4 *)(xp + kc * 32);
    f32x4 xb = *(const f32x4 *)(xp + kc * 32 + 4);
    union { u16 u[8]; bf16x8 v; } H, L;
#pragma unroll
    for (int e = 0; e < 4; ++e) {
      splitbf(xa[e], H.u[e], L.u[e]);
      splitbf(xb[e], H.u[4 + e], L.u[4 + e]);
    }
    bf16x8 bh = *(const bf16x8 *)(wh + kc * 512);
    bf16x8 bl = *(const bf16x8 *)(wl + kc * 512);
    acc = MFMA16(H.v, bh, acc);
    acc = MFMA16(H.v, bl, acc);
    acc = MFMA16(L.v, bh, acc);
  }
  // k >= 512: h half from LDS
#pragma unroll
  for (int kc = 0; kc < 16; ++kc) {
    bf16x8 Ah = *(const bf16x8 *)(lds + (kc * 64 + ln) * 8);
    bf16x8 Al = *(const bf16x8 *)(lds + 8192 + (kc * 64 + ln) * 8);
    bf16x8 bh = *(const bf16x8 *)(wh + (16 + kc) * 512);
    bf16x8 bl = *(const bf16x8 *)(wl + (16 + kc) * 512);
    acc = MFMA16(Ah, bh, acc);
    acc = MFMA16(Ah, bl, acc);
    acc = MFMA16(Al, bh, acc);
  }
  float sv[4];
  act2<0, true>(acc, spv, S, 1, rt, cb, l4, l15, sv);
}

// hierarchical epoch barrier over 256 WGs (8 clusters x 32)
__device__ __forceinline__ void gbar(u32 *cnt, u32 &ep) {
  __syncthreads();  // drains vmcnt for all waves -> sc-stores at LLC
  ep += 256u;
  if (threadIdx.x == 0) {
    const int c = blockIdx.x & 7;
    u32 old = __hip_atomic_fetch_add(&cnt[c * 64], 1u, __ATOMIC_RELAXED, __HIP_MEMORY_SCOPE_AGENT);
    if (((old + 1u) & 31u) == 0u)
      __hip_atomic_fetch_add(&cnt[512], 32u, __ATOMIC_RELAXED, __HIP_MEMORY_SCOPE_AGENT);
    while (__hip_atomic_load(&cnt[512], __ATOMIC_RELAXED, __HIP_MEMORY_SCOPE_AGENT) < ep)
      __builtin_amdgcn_s_sleep(2);
  }
  __syncthreads();
}

__global__ __launch_bounds__(256, 1) void darts_rnn(
    const float *__restrict__ xin, const float *__restrict__ h0in,
    const float *__restrict__ W0, const float *__restrict__ Wsi,
    float *__restrict__ out, u16 *__restrict__ wsu) {
  __shared__ u16 smem[16384];  // 32KB: one (slot,rt) panel, hi-plane ++ lo-plane
  u32 *cnt = (u32 *)wsu;
  u16 *Wh = wsu + 2048;        // byte 4096
  u16 *Wl = Wh + 5242880;
  u16 *S = Wl + 5242880;

  const int tid = threadIdx.x, bid = blockIdx.x;
  const int ln = tid & 63, wid = tid >> 6;
  const int l15 = ln & 15, l4 = ln >> 4;
  const int rt = (bid & 127) >> 4;
  const int cb = ((bid & 15) * 4 + wid) & 63;

  u32 ep = 0;

  // ---- cache hygiene: flush dirty ws lines (poison), then invalidate L2 ----
  if (wid == 0) asm volatile("buffer_wbl2 sc1" ::: "memory");
  wait_vm();
  gbar(cnt, ep);
  if (wid == 0) asm volatile("buffer_inv sc1" ::: "memory");
  wait_vm();
  gbar(cnt, ep);

  // ---- P0: weight hi/lo split into fragment layout (coalesced reads) ----
  for (int idx = bid * 256 + tid; idx < 5242880; idx += 65536) {
    int mk = idx >> 10, oc = idx & 1023;
    int m, k;
    if (mk < 1024) { m = 0; k = mk; } else { m = 1 + ((mk - 1024) >> 9); k = (mk - 1024) & 511; }
    float v = (m == 0) ? W0[k * 1024 + oc] : Wsi[((m - 1) * 512 + k) * 1024 + oc];
    int colp = (oc < 512) ? (oc * 2) : ((oc - 512) * 2 + 1);  // interleave c,h cols
    int cbw = colp >> 4;
    int kc = k >> 5;
    int lnn = (colp & 15) + ((k >> 3) & 3) * 16;
    int el = k & 7;
    // W0 has K=1024 -> 32 kc-chunks per cb; Ws have K=512 -> 16. (Round-3 bug:
    // used cbw*16 for both, garbling W0's fragments.)
    int lineBase = (m == 0) ? (cbw * 32 + kc) : (cbw * 16 + kc);
    int e = mbase(m) + (lineBase * 64 + lnn) * 8 + el;
    u16 hi, lo; splitbf(v, hi, lo);
    st16_sc(Wh + e, hi);
    st16_sc(Wl + e, lo);
  }
  {  // h0 -> slot 0
    int g = bid * 256 + tid;         // 65536 = 128*512
    int row = g >> 9, k = g & 511;
    u16 hi, lo; splitbf(h0in[g], hi, lo);
    int o = goff(0, row, k);
    st16_sc(S + o, hi);
    st16_sc(S + o + 8192, lo);
  }
  gbar(cnt, ep);

  float d0[4], d1[4];
  for (int t = 0; t < 256; ++t) {
    // ---- round A: s0 (slot1); blocks 0..127 ----
    if (bid < 128) {
      stage_panel(S, 0, rt, smem, tid);
      __syncthreads();
      roundA(xin, t, Wh, Wl, S, smem, rt, cb, ln, l4, l15);
    }
    gbar(cnt, ep);
    // ---- round B: s1 <- Ws0(sigmoid) on s0 ----
    if (bid < 128) {
      stage_panel(S, 1, rt, smem, tid);
      __syncthreads();
      gemm512<1, 1, false, true>(Wh, Wl, S, smem, 1, 1, 2, 2, rt, cb, ln, l4, l15, d0, d1);
    }
    gbar(cnt, ep);
    // ---- round C: s2<-Ws1(relu), s4<-Ws3(ident) | s3<-Ws2(relu); A = s1 ----
    stage_panel(S, 2, rt, smem, tid);
    __syncthreads();
    if (bid < 128)
      gemm512<2, 3, true, true>(Wh, Wl, S, smem, 2, 4, 3, 5, rt, cb, ln, l4, l15, d0, d1);
    else
      gemm512<2, 2, false, true>(Wh, Wl, S, smem, 3, 3, 4, 4, rt, cb, ln, l4, l15, d0, d1);
    gbar(cnt, ep);
    // ---- round D: s5<-Ws4(tanh) on s2 | s7<-Ws6(tanh) on s3 ----
    stage_panel(S, (bid < 128) ? 3 : 4, rt, smem, tid);
    __syncthreads();
    if (bid < 128)
      gemm512<0, 0, false, true>(Wh, Wl, S, smem, 5, 5, 6, 6, rt, cb, ln, l4, l15, d0, d1);
    else
      gemm512<0, 0, false, true>(Wh, Wl, S, smem, 7, 7, 7, 7, rt, cb, ln, l4, l15, d0, d1);
    gbar(cnt, ep);
    // ---- round E: s6<-Ws5(sig), s8<-Ws7(relu) on s5; fused mean -> out, h ----
    if (bid < 128) {
      stage_panel(S, 6, rt, smem, tid);
      __syncthreads();
      float sv6[4], sv8[4];
      gemm512<1, 2, true, false>(Wh, Wl, S, smem, 6, 8, 0, 0, rt, cb, ln, l4, l15, sv6, sv8);
      u32 mh[6][4], ml[6][4];
#pragma unroll
      for (int s = 0; s < 6; ++s)
#pragma unroll
        for (int j = 0; j < 4; ++j) {
          int row = rt * 16 + l4 * 4 + j, scol = cb * 8 + (l15 >> 1);
          const u16 *p = S + goff(s + 2, row, scol);  // slots 2..7 = s1..s5,s7
          issue_ldu16_sc(mh[s][j], p);
          issue_ldu16_sc(ml[s][j], p + 8192);
        }
      wait_vm();
      if ((l15 & 1) == 0) {
#pragma unroll
        for (int j = 0; j < 4; ++j) {
          float sum = sv6[j] + sv8[j];
#pragma unroll
          for (int s = 0; s < 6; ++s) sum += bf2f(mh[s][j]) + bf2f(ml[s][j]);
          float hnew = sum * 0.125f;
          int row = rt * 16 + l4 * 4 + j, scol = cb * 8 + (l15 >> 1);
          out[t * 65536 + row * 512 + scol] = hnew;
          if (t == 255) out[16777216 + row * 512 + scol] = hnew;
          u16 hi, lo; splitbf(hnew, hi, lo);
          int o = goff(0, row, scol);
          st16_sc(S + o, hi);
          st16_sc(S + o + 8192, lo);
        }
      }
    }
    gbar(cnt, ep);
  }
}

extern "C" void kernel_launch(void *const *d_in, const int *in_sizes, int n_in,
                              void *d_out, int out_size, void *d_ws, size_t ws_size,
                              hipStream_t stream) {
  const float *x = (const float *)d_in[0];
  const float *h0 = (const float *)d_in[1];
  const float *W0 = (const float *)d_in[2];
  const float *Ws = (const float *)d_in[3];
  float *out = (float *)d_out;
  u16 *ws = (u16 *)d_ws;

  hipMemsetAsync(d_ws, 0, 4096, stream);  // zero barrier counters

  void *args[] = {(void *)&x, (void *)&h0, (void *)&W0, (void *)&Ws, (void *)&out, (void *)&ws};
  hipError_t err = hipLaunchCooperativeKernel((void *)darts_rnn, dim3(256), dim3(256),
                                              args, 0, stream);
  if (err != hipSuccess) {
    (void)hipGetLastError();
    darts_rnn<<<dim3(256), dim3(256), 0, stream>>>(x, h0, W0, Ws, out, ws);
  }
}